// Round 1
// baseline (266.406 us; speedup 1.0000x reference)
//
#include <hip/hip_runtime.h>
#include <cstdint>
#include <cstddef>

#define NCLS 80
#define KTOP 10
#define NG   20
#define NB   32
#define A0   6400
#define A1   1600
#define A2   400
#define ATOT 8400
#define EPSF 1e-9f

// ---------------------------------------------------------------------------
// Phase 1: per (b, anchor): softmax stats + per-gt alignment metric
// metric layout: metric[(b*NG + g)*ATOT + a]  (contiguous in a for phase 2)
// ---------------------------------------------------------------------------
__global__ __launch_bounds__(256) void phase1_metric(
    const float* __restrict__ cls0, const float* __restrict__ reg0,
    const float* __restrict__ cls1, const float* __restrict__ reg1,
    const float* __restrict__ cls2, const float* __restrict__ reg2,
    const float* __restrict__ anchors, const float* __restrict__ gtb,
    const int* __restrict__ gtl,
    float* __restrict__ metric, float* __restrict__ logZ)
{
    int t = blockIdx.x * 256 + threadIdx.x;
    if (t >= NB * ATOT) return;
    int b = t / ATOT, a = t % ATOT;

    const float* cls; const float* reg; int off, A; float stride;
    if (a < A0)           { cls = cls0; reg = reg0; off = 0;     A = A0; stride = 8.f;  }
    else if (a < A0 + A1) { cls = cls1; reg = reg1; off = A0;    A = A1; stride = 16.f; }
    else                  { cls = cls2; reg = reg2; off = A0+A1; A = A2; stride = 32.f; }
    int al = a - off;

    const float* crow = cls + ((size_t)b * A + al) * NCLS;
    float m = -1e30f;
    for (int c = 0; c < NCLS; ++c) m = fmaxf(m, crow[c]);
    float s = 0.f;
    for (int c = 0; c < NCLS; ++c) s += expf(crow[c] - m);
    float lz = m + logf(s);
    logZ[(size_t)b * ATOT + a] = lz;

    float ax = anchors[2 * a]     * stride;
    float ay = anchors[2 * a + 1] * stride;
    const float* rr = reg + ((size_t)b * A + al) * 4;
    float px1 = ax - rr[0] * stride, py1 = ay - rr[1] * stride;
    float px2 = ax + rr[2] * stride, py2 = ay + rr[3] * stride;
    float area1 = (px2 - px1) * (py2 - py1);

    const float* gb = gtb + (size_t)b * NG * 4;
    const int*   gl = gtl + (size_t)b * NG;

    for (int g = 0; g < NG; ++g) {
        float gx1 = gb[4*g], gy1 = gb[4*g+1], gx2 = gb[4*g+2], gy2 = gb[4*g+3];
        float met = 0.f;
        bool ing = (ax - gx1 > EPSF) && (ay - gy1 > EPSF) &&
                   (gx2 - ax > EPSF) && (gy2 - ay > EPSF);
        if (ing) {
            float ltx = fmaxf(px1, gx1), lty = fmaxf(py1, gy1);
            float rbx = fminf(px2, gx2), rby = fminf(py2, gy2);
            float w = fmaxf(rbx - ltx, 0.f), h = fmaxf(rby - lty, 0.f);
            float inter = w * h;
            float area2 = (gx2 - gx1) * (gy2 - gy1);
            float iou = inter / (area1 + area2 - inter + EPSF);
            float sc = expf(crow[gl[g]] - lz);        // softmax score at gt label
            float i2 = iou * iou;
            met = sc * (i2 * i2 * i2);                // score^1 * iou^6
        }
        metric[((size_t)(b * NG + g)) * ATOT + a] = met;
    }
}

// ---------------------------------------------------------------------------
// Phase 2: exact top-10 per (b, g, level) with jax.lax.top_k tie-breaking
// (value desc, then index asc). Sets bit g of mask[b][a] when val > EPS.
// ---------------------------------------------------------------------------
__global__ __launch_bounds__(256) void phase2_topk(
    const float* __restrict__ metric, uint32_t* __restrict__ mask)
{
    int id  = blockIdx.x;          // [0, NB*NG*3)
    int lvl = id % 3;
    int bg  = id / 3;              // b*NG + g
    int b = bg / NG, g = bg % NG;
    int off, A;
    if (lvl == 0)      { off = 0;     A = A0; }
    else if (lvl == 1) { off = A0;    A = A1; }
    else               { off = A0+A1; A = A2; }

    const float* met = metric + (size_t)bg * ATOT + off;

    __shared__ float sval[A0];
    __shared__ float rv[256];
    __shared__ int   ri[256];
    int tid = threadIdx.x;

    for (int i = tid; i < A; i += 256) sval[i] = met[i];
    __syncthreads();

    for (int k = 0; k < KTOP; ++k) {
        float bv = -1.f; int bi = 1 << 30;
        for (int i = tid; i < A; i += 256) {
            float v = sval[i];
            if (v > bv) { bv = v; bi = i; }   // ascending scan: strict > keeps lowest idx on ties
        }
        rv[tid] = bv; ri[tid] = bi;
        __syncthreads();
        for (int sft = 128; sft > 0; sft >>= 1) {
            if (tid < sft) {
                float ov = rv[tid + sft]; int oi = ri[tid + sft];
                if (ov > rv[tid] || (ov == rv[tid] && oi < ri[tid])) { rv[tid] = ov; ri[tid] = oi; }
            }
            __syncthreads();
        }
        float wv = rv[0]; int wi = ri[0];
        if (wv <= EPSF) break;                 // uniform: all threads read rv[0]
        if (tid == 0) {
            atomicOr(&mask[(size_t)b * ATOT + off + wi], 1u << g);
            sval[wi] = -1.f;
        }
        __syncthreads();
    }
}

// ---------------------------------------------------------------------------
// Phase 3: resolve multi-assignment by best IoU, accumulate CE loss + count
// ---------------------------------------------------------------------------
__global__ __launch_bounds__(256) void phase3_loss(
    const float* __restrict__ cls0, const float* __restrict__ reg0,
    const float* __restrict__ cls1, const float* __restrict__ reg1,
    const float* __restrict__ cls2, const float* __restrict__ reg2,
    const float* __restrict__ anchors, const float* __restrict__ gtb,
    const int* __restrict__ gtl,
    const uint32_t* __restrict__ mask, const float* __restrict__ logZ,
    float* __restrict__ lossAcc, int* __restrict__ cntAcc)
{
    int t = blockIdx.x * 256 + threadIdx.x;
    if (t >= NB * ATOT) return;
    int b = t / ATOT, a = t % ATOT;

    uint32_t mk = mask[(size_t)b * ATOT + a];
    if (!mk) return;

    const float* cls; const float* reg; int off, A; float stride;
    if (a < A0)           { cls = cls0; reg = reg0; off = 0;     A = A0; stride = 8.f;  }
    else if (a < A0 + A1) { cls = cls1; reg = reg1; off = A0;    A = A1; stride = 16.f; }
    else                  { cls = cls2; reg = reg2; off = A0+A1; A = A2; stride = 32.f; }
    int al = a - off;

    float ax = anchors[2 * a]     * stride;
    float ay = anchors[2 * a + 1] * stride;
    const float* rr = reg + ((size_t)b * A + al) * 4;
    float px1 = ax - rr[0] * stride, py1 = ay - rr[1] * stride;
    float px2 = ax + rr[2] * stride, py2 = ay + rr[3] * stride;
    float area1 = (px2 - px1) * (py2 - py1);

    const float* gb = gtb + (size_t)b * NG * 4;

    float bestI = -1.f; int bestG = 0;
    uint32_t mm = mk;
    while (mm) {
        int g = __ffs(mm) - 1; mm &= mm - 1;
        float gx1 = gb[4*g], gy1 = gb[4*g+1], gx2 = gb[4*g+2], gy2 = gb[4*g+3];
        float ltx = fmaxf(px1, gx1), lty = fmaxf(py1, gy1);
        float rbx = fminf(px2, gx2), rby = fminf(py2, gy2);
        float w = fmaxf(rbx - ltx, 0.f), h = fmaxf(rby - lty, 0.f);
        float inter = w * h;
        float area2 = (gx2 - gx1) * (gy2 - gy1);
        float iou = inter / (area1 + area2 - inter + EPSF);
        if (iou > bestI) { bestI = iou; bestG = g; }   // ascending g: ties keep lowest (jnp.argmax)
    }
    // n_assign==1: single bit == bestG; n_assign>1: keep best-IoU gt. Either way bestG.
    int tl = gtl[b * NG + bestG];
    const float* crow = cls + ((size_t)b * A + al) * NCLS;
    float ce = logZ[(size_t)b * ATOT + a] - crow[tl];  // -log_softmax[target]

    atomicAdd(lossAcc, ce);
    atomicAdd(cntAcc, 1);
}

__global__ void finalize_loss(const float* __restrict__ lossAcc,
                              const int* __restrict__ cntAcc,
                              float* __restrict__ out)
{
    int n = *cntAcc;
    float denom = (float)(n < 1 ? 1 : n);
    out[0] = *lossAcc / denom;
    out[1] = (float)n;
}

extern "C" void kernel_launch(void* const* d_in, const int* in_sizes, int n_in,
                              void* d_out, int out_size, void* d_ws, size_t ws_size,
                              hipStream_t stream)
{
    // setup_inputs() dict order: cls0, reg0, cls1, reg1, cls2, reg2, anchors, gt_boxes, gt_labels
    const float* cls0 = (const float*)d_in[0];
    const float* reg0 = (const float*)d_in[1];
    const float* cls1 = (const float*)d_in[2];
    const float* reg1 = (const float*)d_in[3];
    const float* cls2 = (const float*)d_in[4];
    const float* reg2 = (const float*)d_in[5];
    const float* anchors = (const float*)d_in[6];
    const float* gtb  = (const float*)d_in[7];
    const int*   gtl  = (const int*)d_in[8];

    float*    metric  = (float*)d_ws;                          // NB*NG*ATOT floats
    float*    logZ    = metric + (size_t)NB * NG * ATOT;       // NB*ATOT floats
    uint32_t* mask    = (uint32_t*)(logZ + (size_t)NB * ATOT); // NB*ATOT u32
    float*    lossAcc = (float*)(mask + (size_t)NB * ATOT);
    int*      cntAcc  = (int*)(lossAcc + 1);

    // zero only mask + accumulators (metric/logZ fully overwritten each call)
    hipMemsetAsync(mask, 0, (size_t)NB * ATOT * sizeof(uint32_t) + 2 * sizeof(float), stream);

    int nthr = NB * ATOT;
    int nblk = (nthr + 255) / 256;
    phase1_metric<<<nblk, 256, 0, stream>>>(cls0, reg0, cls1, reg1, cls2, reg2,
                                            anchors, gtb, gtl, metric, logZ);
    phase2_topk<<<NB * NG * 3, 256, 0, stream>>>(metric, mask);
    phase3_loss<<<nblk, 256, 0, stream>>>(cls0, reg0, cls1, reg1, cls2, reg2,
                                          anchors, gtb, gtl, mask, logZ, lossAcc, cntAcc);
    finalize_loss<<<1, 1, 0, stream>>>(lossAcc, cntAcc, (float*)d_out);
}

// Round 2
// 156.859 us; speedup vs baseline: 1.6984x; 1.6984x over previous
//
#include <hip/hip_runtime.h>
#include <cstdint>
#include <cstddef>

#define NCLS 80
#define KTOP 10
#define NG   20
#define NB   32
#define A0   6400
#define A1   1600
#define A2   400
#define ATOT 8400
#define EPSF 1e-9f
#define CAP  512      // max in-box anchors per (b,g,level): boxes <=136px -> <=18^2=324

// ---------------------------------------------------------------------------
// Phase 1: per (b, anchor): softmax stats (vectorized float4 row load) +
// per-gt alignment metric; appends (val, a) candidates per (b,g,level) list.
// ---------------------------------------------------------------------------
__global__ __launch_bounds__(256) void phase1_metric(
    const float* __restrict__ cls0, const float* __restrict__ reg0,
    const float* __restrict__ cls1, const float* __restrict__ reg1,
    const float* __restrict__ cls2, const float* __restrict__ reg2,
    const float* __restrict__ anchors, const float* __restrict__ gtb,
    const int* __restrict__ gtl,
    float* __restrict__ logZ, int* __restrict__ cnt,
    float* __restrict__ cval, int* __restrict__ cidx)
{
    int t = blockIdx.x * 256 + threadIdx.x;
    if (t >= NB * ATOT) return;
    int b = t / ATOT, a = t % ATOT;

    const float* cls; const float* reg; int off, A, lvl; float stride;
    if (a < A0)           { cls = cls0; reg = reg0; off = 0;     A = A0; lvl = 0; stride = 8.f;  }
    else if (a < A0 + A1) { cls = cls1; reg = reg1; off = A0;    A = A1; lvl = 1; stride = 16.f; }
    else                  { cls = cls2; reg = reg2; off = A0+A1; A = A2; lvl = 2; stride = 32.f; }
    int al = a - off;

    const float* crow = cls + ((size_t)b * A + al) * NCLS;

    // gather label scores early (hides latency under the row stream below)
    int lbl[NG];
    #pragma unroll
    for (int g = 0; g < NG; ++g) lbl[g] = gtl[b * NG + g];
    float craw[NG];
    #pragma unroll
    for (int g = 0; g < NG; ++g) craw[g] = crow[lbl[g]];

    // stream the 80-class row as 20 aligned float4 loads, keep in registers
    const float4* crow4 = reinterpret_cast<const float4*>(crow);
    float r[NCLS];
    float m = -1e30f;
    #pragma unroll
    for (int j = 0; j < NCLS / 4; ++j) {
        float4 v = crow4[j];
        r[4*j+0] = v.x; r[4*j+1] = v.y; r[4*j+2] = v.z; r[4*j+3] = v.w;
        m = fmaxf(m, fmaxf(fmaxf(v.x, v.y), fmaxf(v.z, v.w)));
    }
    float s = 0.f;
    #pragma unroll
    for (int c = 0; c < NCLS; ++c) s += __expf(r[c] - m);
    float lz = m + __logf(s);
    logZ[(size_t)b * ATOT + a] = lz;

    float ax = anchors[2 * a]     * stride;
    float ay = anchors[2 * a + 1] * stride;
    float4 rr = *reinterpret_cast<const float4*>(reg + ((size_t)b * A + al) * 4);
    float px1 = ax - rr.x * stride, py1 = ay - rr.y * stride;
    float px2 = ax + rr.z * stride, py2 = ay + rr.w * stride;
    float area1 = (px2 - px1) * (py2 - py1);

    const float* gb = gtb + (size_t)b * NG * 4;

    #pragma unroll 4
    for (int g = 0; g < NG; ++g) {
        float gx1 = gb[4*g], gy1 = gb[4*g+1], gx2 = gb[4*g+2], gy2 = gb[4*g+3];
        bool ing = (ax - gx1 > EPSF) && (ay - gy1 > EPSF) &&
                   (gx2 - ax > EPSF) && (gy2 - ay > EPSF);
        if (ing) {
            float ltx = fmaxf(px1, gx1), lty = fmaxf(py1, gy1);
            float rbx = fminf(px2, gx2), rby = fminf(py2, gy2);
            float w = fmaxf(rbx - ltx, 0.f), h = fmaxf(rby - lty, 0.f);
            float inter = w * h;
            float area2 = (gx2 - gx1) * (gy2 - gy1);
            float iou = inter / (area1 + area2 - inter + EPSF);
            float sc = __expf(craw[g] - lz);          // softmax score at gt label
            float i2 = iou * iou;
            float met = sc * (i2 * i2 * i2);          // score^1 * iou^6
            if (met > EPSF) {
                int list = (b * NG + g) * 3 + lvl;
                int slot = atomicAdd(&cnt[list], 1);
                if (slot < CAP) {
                    cval[(size_t)list * CAP + slot] = met;
                    cidx[(size_t)list * CAP + slot] = a;  // global anchor idx (same order as local)
                }
            }
        }
    }
}

// ---------------------------------------------------------------------------
// Phase 2: exact top-10 per (b,g,level) over the compacted candidate list.
// Sort key = (val_bits << 32) | (ATOT - a): max key == (val desc, idx asc),
// identical tie-break to jax.lax.top_k. All candidates are > EPS by
// construction, so n<=KTOP means all are selected.
// ---------------------------------------------------------------------------
__global__ __launch_bounds__(64) void phase2_topk(
    const int* __restrict__ cnt, const float* __restrict__ cval,
    const int* __restrict__ cidx, uint32_t* __restrict__ mask)
{
    int id = blockIdx.x;            // (b*NG+g)*3 + lvl
    int bg = id / 3;
    int b = bg / NG, g = bg % NG;
    uint32_t bit = 1u << g;
    int lane = threadIdx.x;

    int n = cnt[id]; if (n > CAP) n = CAP;
    if (n == 0) return;

    const float* v  = cval + (size_t)id * CAP;
    const int*   ix = cidx + (size_t)id * CAP;

    if (n <= KTOP) {
        for (int i = lane; i < n; i += 64)
            atomicOr(&mask[(size_t)b * ATOT + ix[i]], bit);
        return;
    }

    __shared__ unsigned long long key[CAP];
    for (int i = lane; i < n; i += 64) {
        uint32_t vb = __float_as_uint(v[i]);                 // val > 0 -> monotonic bits
        key[i] = ((unsigned long long)vb << 32) | (uint32_t)(ATOT - ix[i]);
    }
    __syncthreads();

    for (int k = 0; k < KTOP; ++k) {
        unsigned long long bk = 0; int bs = -1;
        for (int i = lane; i < n; i += 64) {
            unsigned long long kk = key[i];
            if (kk > bk) { bk = kk; bs = i; }
        }
        #pragma unroll
        for (int sft = 32; sft > 0; sft >>= 1) {
            unsigned long long ok = __shfl_down(bk, sft);
            int os = __shfl_down(bs, sft);
            if (ok > bk) { bk = ok; bs = os; }
        }
        if (lane == 0) {
            int aa = ATOT - (int)(bk & 0xffffffffu);
            atomicOr(&mask[(size_t)b * ATOT + aa], bit);
            key[bs] = 0;                                     // remove winner
        }
        __syncthreads();
    }
}

// ---------------------------------------------------------------------------
// Phase 3: resolve multi-assignment by best IoU, accumulate CE loss + count
// ---------------------------------------------------------------------------
__global__ __launch_bounds__(256) void phase3_loss(
    const float* __restrict__ cls0, const float* __restrict__ reg0,
    const float* __restrict__ cls1, const float* __restrict__ reg1,
    const float* __restrict__ cls2, const float* __restrict__ reg2,
    const float* __restrict__ anchors, const float* __restrict__ gtb,
    const int* __restrict__ gtl,
    const uint32_t* __restrict__ mask, const float* __restrict__ logZ,
    float* __restrict__ lossAcc, int* __restrict__ cntAcc)
{
    int t = blockIdx.x * 256 + threadIdx.x;
    if (t >= NB * ATOT) return;
    int b = t / ATOT, a = t % ATOT;

    uint32_t mk = mask[(size_t)b * ATOT + a];
    if (!mk) return;

    const float* cls; const float* reg; int off, A; float stride;
    if (a < A0)           { cls = cls0; reg = reg0; off = 0;     A = A0; stride = 8.f;  }
    else if (a < A0 + A1) { cls = cls1; reg = reg1; off = A0;    A = A1; stride = 16.f; }
    else                  { cls = cls2; reg = reg2; off = A0+A1; A = A2; stride = 32.f; }
    int al = a - off;

    float ax = anchors[2 * a]     * stride;
    float ay = anchors[2 * a + 1] * stride;
    float4 rr = *reinterpret_cast<const float4*>(reg + ((size_t)b * A + al) * 4);
    float px1 = ax - rr.x * stride, py1 = ay - rr.y * stride;
    float px2 = ax + rr.z * stride, py2 = ay + rr.w * stride;
    float area1 = (px2 - px1) * (py2 - py1);

    const float* gb = gtb + (size_t)b * NG * 4;

    float bestI = -1.f; int bestG = 0;
    uint32_t mm = mk;
    while (mm) {
        int g = __ffs(mm) - 1; mm &= mm - 1;
        float gx1 = gb[4*g], gy1 = gb[4*g+1], gx2 = gb[4*g+2], gy2 = gb[4*g+3];
        float ltx = fmaxf(px1, gx1), lty = fmaxf(py1, gy1);
        float rbx = fminf(px2, gx2), rby = fminf(py2, gy2);
        float w = fmaxf(rbx - ltx, 0.f), h = fmaxf(rby - lty, 0.f);
        float inter = w * h;
        float area2 = (gx2 - gx1) * (gy2 - gy1);
        float iou = inter / (area1 + area2 - inter + EPSF);
        if (iou > bestI) { bestI = iou; bestG = g; }   // ascending g: ties keep lowest (jnp.argmax)
    }
    int tl = gtl[b * NG + bestG];
    const float* crow = cls + ((size_t)b * A + al) * NCLS;
    float ce = logZ[(size_t)b * ATOT + a] - crow[tl];  // -log_softmax[target]

    atomicAdd(lossAcc, ce);
    atomicAdd(cntAcc, 1);
}

__global__ void finalize_loss(const float* __restrict__ lossAcc,
                              const int* __restrict__ cntAcc,
                              float* __restrict__ out)
{
    int n = *cntAcc;
    float denom = (float)(n < 1 ? 1 : n);
    out[0] = *lossAcc / denom;
    out[1] = (float)n;
}

extern "C" void kernel_launch(void* const* d_in, const int* in_sizes, int n_in,
                              void* d_out, int out_size, void* d_ws, size_t ws_size,
                              hipStream_t stream)
{
    const float* cls0 = (const float*)d_in[0];
    const float* reg0 = (const float*)d_in[1];
    const float* cls1 = (const float*)d_in[2];
    const float* reg1 = (const float*)d_in[3];
    const float* cls2 = (const float*)d_in[4];
    const float* reg2 = (const float*)d_in[5];
    const float* anchors = (const float*)d_in[6];
    const float* gtb  = (const float*)d_in[7];
    const int*   gtl  = (const int*)d_in[8];

    // workspace layout
    float*    logZ    = (float*)d_ws;                              // NB*ATOT
    uint32_t* mask    = (uint32_t*)(logZ + (size_t)NB * ATOT);     // NB*ATOT
    int*      cnt     = (int*)(mask + (size_t)NB * ATOT);          // NB*NG*3
    float*    lossAcc = (float*)(cnt + NB * NG * 3);
    int*      cntAcc  = (int*)(lossAcc + 1);
    float*    cval    = (float*)(cntAcc + 1);                      // NB*NG*3*CAP
    int*      cidx    = (int*)(cval + (size_t)NB * NG * 3 * CAP);  // NB*NG*3*CAP

    // zero mask + counters + accumulators (one contiguous span)
    size_t zbytes = (size_t)NB * ATOT * sizeof(uint32_t)
                  + (size_t)NB * NG * 3 * sizeof(int) + 2 * sizeof(float);
    hipMemsetAsync(mask, 0, zbytes, stream);

    int nthr = NB * ATOT;
    int nblk = (nthr + 255) / 256;
    phase1_metric<<<nblk, 256, 0, stream>>>(cls0, reg0, cls1, reg1, cls2, reg2,
                                            anchors, gtb, gtl, logZ, cnt, cval, cidx);
    phase2_topk<<<NB * NG * 3, 64, 0, stream>>>(cnt, cval, cidx, mask);
    phase3_loss<<<nblk, 256, 0, stream>>>(cls0, reg0, cls1, reg1, cls2, reg2,
                                          anchors, gtb, gtl, mask, logZ, lossAcc, cntAcc);
    finalize_loss<<<1, 1, 0, stream>>>(lossAcc, cntAcc, (float*)d_out);
}

// Round 3
// 72.278 us; speedup vs baseline: 3.6858x; 2.1702x over previous
//
#include <hip/hip_runtime.h>
#include <cstdint>
#include <cstddef>

#define NCLS 80
#define KTOP 10
#define NG   20
#define NB   32
#define A0   6400
#define A1   1600
#define A2   400
#define ATOT 8400
#define EPSF 1e-9f
#define CAP  512      // max in-box anchors per (b,g,level): boxes <=136px -> <=18^2=324

// ---------------------------------------------------------------------------
// Phase 1: per (b, anchor): in-box test FIRST (cheap: reg + broadcast boxes);
// only anchors inside >=1 gt box load the 80-class row and do the softmax.
// Appends (val, a) candidates per (b,g,level) list.
// ---------------------------------------------------------------------------
__global__ __launch_bounds__(256) void phase1_metric(
    const float* __restrict__ cls0, const float* __restrict__ reg0,
    const float* __restrict__ cls1, const float* __restrict__ reg1,
    const float* __restrict__ cls2, const float* __restrict__ reg2,
    const float* __restrict__ anchors, const float* __restrict__ gtb,
    const int* __restrict__ gtl,
    float* __restrict__ logZ, int* __restrict__ cnt,
    float* __restrict__ cval, int* __restrict__ cidx)
{
    int t = blockIdx.x * 256 + threadIdx.x;
    if (t >= NB * ATOT) return;
    int b = t / ATOT, a = t % ATOT;

    const float* cls; const float* reg; int off, A, lvl; float stride;
    if (a < A0)           { cls = cls0; reg = reg0; off = 0;     A = A0; lvl = 0; stride = 8.f;  }
    else if (a < A0 + A1) { cls = cls1; reg = reg1; off = A0;    A = A1; lvl = 1; stride = 16.f; }
    else                  { cls = cls2; reg = reg2; off = A0+A1; A = A2; lvl = 2; stride = 32.f; }
    int al = a - off;

    float ax = anchors[2 * a]     * stride;
    float ay = anchors[2 * a + 1] * stride;

    // in-box test over all 20 gts (broadcast loads, L1/L2 hit)
    const float4* gb4 = reinterpret_cast<const float4*>(gtb + (size_t)b * NG * 4);
    uint32_t ingMask = 0;
    #pragma unroll
    for (int g = 0; g < NG; ++g) {
        float4 gv = gb4[g];
        bool ing = (ax - gv.x > EPSF) && (ay - gv.y > EPSF) &&
                   (gv.z - ax > EPSF) && (gv.w - ay > EPSF);
        if (ing) ingMask |= (1u << g);
    }
    if (!ingMask) return;   // ~75% of anchors: skip the 320B cls row entirely

    // predicted box
    float4 rr = *reinterpret_cast<const float4*>(reg + ((size_t)b * A + al) * 4);
    float px1 = ax - rr.x * stride, py1 = ay - rr.y * stride;
    float px2 = ax + rr.z * stride, py2 = ay + rr.w * stride;
    float area1 = (px2 - px1) * (py2 - py1);

    // softmax stats: 20 aligned float4 loads, kept in registers
    const float* crow = cls + ((size_t)b * A + al) * NCLS;
    const float4* crow4 = reinterpret_cast<const float4*>(crow);
    float r[NCLS];
    float m = -1e30f;
    #pragma unroll
    for (int j = 0; j < NCLS / 4; ++j) {
        float4 v = crow4[j];
        r[4*j+0] = v.x; r[4*j+1] = v.y; r[4*j+2] = v.z; r[4*j+3] = v.w;
        m = fmaxf(m, fmaxf(fmaxf(v.x, v.y), fmaxf(v.z, v.w)));
    }
    float s = 0.f;
    #pragma unroll
    for (int c = 0; c < NCLS; ++c) s += __expf(r[c] - m);
    float lz = m + __logf(s);
    logZ[(size_t)b * ATOT + a] = lz;

    const int* gl = gtl + b * NG;

    uint32_t mm = ingMask;
    while (mm) {
        int g = __ffs(mm) - 1; mm &= mm - 1;
        float4 gv = gb4[g];
        float ltx = fmaxf(px1, gv.x), lty = fmaxf(py1, gv.y);
        float rbx = fminf(px2, gv.z), rby = fminf(py2, gv.w);
        float w = fmaxf(rbx - ltx, 0.f), h = fmaxf(rby - lty, 0.f);
        float inter = w * h;
        float area2 = (gv.z - gv.x) * (gv.w - gv.y);
        float iou = inter / (area1 + area2 - inter + EPSF);
        float sc = __expf(crow[gl[g]] - lz);      // softmax score at gt label (L1-hot row)
        float i2 = iou * iou;
        float met = sc * (i2 * i2 * i2);          // score^1 * iou^6
        if (met > EPSF) {
            int list = (b * NG + g) * 3 + lvl;
            int slot = atomicAdd(&cnt[list], 1);
            if (slot < CAP) {
                cval[(size_t)list * CAP + slot] = met;
                cidx[(size_t)list * CAP + slot] = a;
            }
        }
    }
}

// ---------------------------------------------------------------------------
// Phase 2: exact top-10 per (b,g,level) over the compacted candidate list.
// Sort key = (val_bits << 32) | (ATOT - a): max key == (val desc, idx asc),
// identical tie-break to jax.lax.top_k. All candidates are > EPS by
// construction, so n<=KTOP means all are selected.
// ---------------------------------------------------------------------------
__global__ __launch_bounds__(64) void phase2_topk(
    const int* __restrict__ cnt, const float* __restrict__ cval,
    const int* __restrict__ cidx, uint32_t* __restrict__ mask)
{
    int id = blockIdx.x;            // (b*NG+g)*3 + lvl
    int bg = id / 3;
    int b = bg / NG, g = bg % NG;
    uint32_t bit = 1u << g;
    int lane = threadIdx.x;

    int n = cnt[id]; if (n > CAP) n = CAP;
    if (n == 0) return;

    const float* v  = cval + (size_t)id * CAP;
    const int*   ix = cidx + (size_t)id * CAP;

    if (n <= KTOP) {
        for (int i = lane; i < n; i += 64)
            atomicOr(&mask[(size_t)b * ATOT + ix[i]], bit);
        return;
    }

    __shared__ unsigned long long key[CAP];
    for (int i = lane; i < n; i += 64) {
        uint32_t vb = __float_as_uint(v[i]);                 // val > 0 -> monotonic bits
        key[i] = ((unsigned long long)vb << 32) | (uint32_t)(ATOT - ix[i]);
    }
    __syncthreads();

    for (int k = 0; k < KTOP; ++k) {
        unsigned long long bk = 0; int bs = -1;
        for (int i = lane; i < n; i += 64) {
            unsigned long long kk = key[i];
            if (kk > bk) { bk = kk; bs = i; }
        }
        #pragma unroll
        for (int sft = 32; sft > 0; sft >>= 1) {
            unsigned long long ok = __shfl_down(bk, sft);
            int os = __shfl_down(bs, sft);
            if (ok > bk) { bk = ok; bs = os; }
        }
        if (lane == 0) {
            int aa = ATOT - (int)(bk & 0xffffffffu);
            atomicOr(&mask[(size_t)b * ATOT + aa], bit);
            key[bs] = 0;                                     // remove winner
        }
        __syncthreads();
    }
}

// ---------------------------------------------------------------------------
// Phase 3: resolve multi-assignment by best IoU; block-reduce CE + count,
// ONE atomic pair per block (kills same-address atomic serialization).
// ---------------------------------------------------------------------------
__global__ __launch_bounds__(256) void phase3_loss(
    const float* __restrict__ cls0, const float* __restrict__ reg0,
    const float* __restrict__ cls1, const float* __restrict__ reg1,
    const float* __restrict__ cls2, const float* __restrict__ reg2,
    const float* __restrict__ anchors, const float* __restrict__ gtb,
    const int* __restrict__ gtl,
    const uint32_t* __restrict__ mask, const float* __restrict__ logZ,
    float* __restrict__ lossAcc, int* __restrict__ cntAcc)
{
    int t = blockIdx.x * 256 + threadIdx.x;
    float ce = 0.f; int pc = 0;

    if (t < NB * ATOT) {
        int b = t / ATOT, a = t % ATOT;
        uint32_t mk = mask[(size_t)b * ATOT + a];
        if (mk) {
            const float* cls; const float* reg; int off, A; float stride;
            if (a < A0)           { cls = cls0; reg = reg0; off = 0;     A = A0; stride = 8.f;  }
            else if (a < A0 + A1) { cls = cls1; reg = reg1; off = A0;    A = A1; stride = 16.f; }
            else                  { cls = cls2; reg = reg2; off = A0+A1; A = A2; stride = 32.f; }
            int al = a - off;

            float ax = anchors[2 * a]     * stride;
            float ay = anchors[2 * a + 1] * stride;
            float4 rr = *reinterpret_cast<const float4*>(reg + ((size_t)b * A + al) * 4);
            float px1 = ax - rr.x * stride, py1 = ay - rr.y * stride;
            float px2 = ax + rr.z * stride, py2 = ay + rr.w * stride;
            float area1 = (px2 - px1) * (py2 - py1);

            const float4* gb4 = reinterpret_cast<const float4*>(gtb + (size_t)b * NG * 4);

            float bestI = -1.f; int bestG = 0;
            uint32_t mm = mk;
            while (mm) {
                int g = __ffs(mm) - 1; mm &= mm - 1;
                float4 gv = gb4[g];
                float ltx = fmaxf(px1, gv.x), lty = fmaxf(py1, gv.y);
                float rbx = fminf(px2, gv.z), rby = fminf(py2, gv.w);
                float w = fmaxf(rbx - ltx, 0.f), h = fmaxf(rby - lty, 0.f);
                float inter = w * h;
                float area2 = (gv.z - gv.x) * (gv.w - gv.y);
                float iou = inter / (area1 + area2 - inter + EPSF);
                if (iou > bestI) { bestI = iou; bestG = g; }   // ascending g: lowest on tie
            }
            int tl = gtl[b * NG + bestG];
            const float* crow = cls + ((size_t)b * A + al) * NCLS;
            ce = logZ[(size_t)b * ATOT + a] - crow[tl];        // -log_softmax[target]
            pc = 1;
        }
    }

    // wave-level reduce (64 lanes)
    #pragma unroll
    for (int sft = 32; sft > 0; sft >>= 1) {
        ce += __shfl_down(ce, sft);
        pc += __shfl_down(pc, sft);
    }
    __shared__ float sce[4];
    __shared__ int   spc[4];
    int wid = threadIdx.x >> 6, lane = threadIdx.x & 63;
    if (lane == 0) { sce[wid] = ce; spc[wid] = pc; }
    __syncthreads();
    if (threadIdx.x == 0) {
        float tce = sce[0] + sce[1] + sce[2] + sce[3];
        int   tpc = spc[0] + spc[1] + spc[2] + spc[3];
        if (tpc) {
            atomicAdd(lossAcc, tce);
            atomicAdd(cntAcc, tpc);
        }
    }
}

__global__ void finalize_loss(const float* __restrict__ lossAcc,
                              const int* __restrict__ cntAcc,
                              float* __restrict__ out)
{
    int n = *cntAcc;
    float denom = (float)(n < 1 ? 1 : n);
    out[0] = *lossAcc / denom;
    out[1] = (float)n;
}

extern "C" void kernel_launch(void* const* d_in, const int* in_sizes, int n_in,
                              void* d_out, int out_size, void* d_ws, size_t ws_size,
                              hipStream_t stream)
{
    const float* cls0 = (const float*)d_in[0];
    const float* reg0 = (const float*)d_in[1];
    const float* cls1 = (const float*)d_in[2];
    const float* reg1 = (const float*)d_in[3];
    const float* cls2 = (const float*)d_in[4];
    const float* reg2 = (const float*)d_in[5];
    const float* anchors = (const float*)d_in[6];
    const float* gtb  = (const float*)d_in[7];
    const int*   gtl  = (const int*)d_in[8];

    // workspace layout
    float*    logZ    = (float*)d_ws;                              // NB*ATOT
    uint32_t* mask    = (uint32_t*)(logZ + (size_t)NB * ATOT);     // NB*ATOT
    int*      cnt     = (int*)(mask + (size_t)NB * ATOT);          // NB*NG*3
    float*    lossAcc = (float*)(cnt + NB * NG * 3);
    int*      cntAcc  = (int*)(lossAcc + 1);
    float*    cval    = (float*)(cntAcc + 1);                      // NB*NG*3*CAP
    int*      cidx    = (int*)(cval + (size_t)NB * NG * 3 * CAP);  // NB*NG*3*CAP

    // zero mask + counters + accumulators (one contiguous span)
    size_t zbytes = (size_t)NB * ATOT * sizeof(uint32_t)
                  + (size_t)NB * NG * 3 * sizeof(int) + 2 * sizeof(float);
    hipMemsetAsync(mask, 0, zbytes, stream);

    int nthr = NB * ATOT;
    int nblk = (nthr + 255) / 256;
    phase1_metric<<<nblk, 256, 0, stream>>>(cls0, reg0, cls1, reg1, cls2, reg2,
                                            anchors, gtb, gtl, logZ, cnt, cval, cidx);
    phase2_topk<<<NB * NG * 3, 64, 0, stream>>>(cnt, cval, cidx, mask);
    phase3_loss<<<nblk, 256, 0, stream>>>(cls0, reg0, cls1, reg1, cls2, reg2,
                                          anchors, gtb, gtl, mask, logZ, lossAcc, cntAcc);
    finalize_loss<<<1, 1, 0, stream>>>(lossAcc, cntAcc, (float*)d_out);
}